// Round 4
// baseline (1437.287 us; speedup 1.0000x reference)
//
#include <hip/hip_runtime.h>
#include <math.h>

typedef _Float16 f16;
typedef _Float16 f16x4 __attribute__((ext_vector_type(4)));
typedef _Float16 f16x8 __attribute__((ext_vector_type(8)));
typedef float f32x4 __attribute__((ext_vector_type(4)));

// ---------------------------------------------------------------------------
// Repack weights (96, V, K) fp32 -> wpack[t][ch][VP] f16, zero-padded v >= V.
// ---------------------------------------------------------------------------
template<int V, int K, int VP>
__global__ void repack_kernel(const float* __restrict__ w, f16* __restrict__ wp) {
    int i = blockIdx.x * 256 + threadIdx.x;
    if (i >= K * 96 * VP) return;
    int v = i % VP, ch = (i / VP) % 96, t = i / (VP * 96);
    float val = (v < V) ? w[(ch * V + v) * K + t] : 0.f;
    wp[i] = (f16)val;
}

// ---------------------------------------------------------------------------
// Conv1d(valid)+bias+relu+maxpool, implicit GEMM on 16x16x32 f16 MFMA.
// Chunked, double-buffered, register-staged pipeline (T14):
//   loads(c+1) issued BEFORE compute(c); LDS write of c+1 after the barrier.
// Each wave computes all 96 channels (6 col-tiles of 16) for 2 row-tiles per
// chunk; B-weights (KT x KS x 6 frags = 192 VGPR) live in registers.
// NS samples per block (ligand=4) amortize the B preload.
// Regs ~250/wave -> 2 waves/SIMD (8 waves/CU, 2 blocks/CU).
// ---------------------------------------------------------------------------
template<int V, int L, int KT, int VP, int KS, int LOUT,
         int NS, int CPS, int CHUNK, int LPB, int LPW, int RSB>
__global__ __launch_bounds__(256, 2) void conv_mfma_kernel(
    const float* __restrict__ in,    // (B*NS, V, L) fp32
    const f16*   __restrict__ wp,    // (KT, 96, VP) f16
    const float* __restrict__ bias,  // (96)
    float* __restrict__ feat,        // (B*NS, 192)
    int feat_off)
{
    constexpr int NC   = NS * CPS;            // total chunks
    constexpr int BUFB = LPB * RSB;           // bytes per LDS buffer
    constexpr int VQ   = (V + 3) / 4;         // vocab quads (last may be tail)
    constexpr int MAXU = (VQ * LPW + 255) / 256;
    static_assert(VP == KS * 32, "one 16x16x32 MFMA covers 32 K per step");

    __shared__ __align__(16) char s_raw[2 * BUFB];
    __shared__ float s_red[4 * 96];

    const int tid  = threadIdx.x;
    const int wave = tid >> 6;
    const int lane = tid & 63;
    const int g    = lane >> 4;        // k-group (0..3): k = g*8+j
    const int r16  = lane & 15;        // A-row / B-col within 16-tile

    // ---- B preload: KT x KS x 6 col-tiles, per-lane contiguous 16B ----
    f16x8 bf[KT][KS][6];
    #pragma unroll
    for (int t = 0; t < KT; ++t)
        #pragma unroll
        for (int ks = 0; ks < KS; ++ks)
            #pragma unroll
            for (int c6 = 0; c6 < 6; ++c6)
                bf[t][ks][c6] = *(const f16x8*)(wp + (t * 96 + c6 * 16 + r16) * VP + ks * 32 + g * 8);

    // ---- register staging ----
    float rs[MAXU][4];
    auto do_loads = [&](int c) {
        const int cs = c / CPS, cbase = (c % CPS) * CHUNK;
        const float* gs = in + ((size_t)blockIdx.x * NS + cs) * (size_t)(V * L);
        #pragma unroll
        for (int u = 0; u < MAXU; ++u) {
            int uu = u * 256 + tid;
            int q4 = uu / LPW, p = uu - q4 * LPW;
            int gp = cbase + p;
            bool pv = (uu < VQ * LPW) && (gp < L);
            #pragma unroll
            for (int j = 0; j < 4; ++j) {
                int v = q4 * 4 + j;
                rs[u][j] = (pv && v < V) ? gs[(size_t)v * L + gp] : 0.f;
            }
        }
    };
    auto do_write = [&](int bsel) {
        char* sb = s_raw + bsel * BUFB;
        #pragma unroll
        for (int u = 0; u < MAXU; ++u) {
            int uu = u * 256 + tid;
            if (uu < VQ * LPW) {
                int q4 = uu / LPW, p = uu - q4 * LPW;
                int swz = ((p >> 2) & 3) << 4;
                char* dst = sb + p * RSB + ((8 * q4) ^ swz);
                if ((q4 + 1) * 4 <= V) {
                    f16x4 hv = { (f16)rs[u][0], (f16)rs[u][1], (f16)rs[u][2], (f16)rs[u][3] };
                    *(f16x4*)dst = hv;
                } else {   // tail quad: pad to 16B with zeros (covers v-pad cols)
                    f16x8 hv = {};
                    #pragma unroll
                    for (int j = 0; j < 4; ++j)
                        if (q4 * 4 + j < V) hv[j] = (f16)rs[u][j];
                    *(f16x8*)dst = hv;
                }
            }
        }
    };

    // rows [LPW, LPB) are identical (zero) in every chunk: fill once
    if constexpr (LPW < LPB) {
        constexpr int NZ = (LPB - LPW) * RSB / 16;
        for (int i = tid; i < 2 * NZ; i += 256) {
            int bsel = i / NZ, off = i % NZ;
            *(f16x8*)(s_raw + bsel * BUFB + LPW * RSB + off * 16) = (f16x8){};
        }
    }

    // ---- pipeline prologue ----
    do_loads(0);
    do_write(0);
    if (NC > 1) do_loads(1);
    __syncthreads();

    float runmax[6];
    #pragma unroll
    for (int c6 = 0; c6 < 6; ++c6) runmax[c6] = -3.0e38f;

    for (int c = 0; c < NC; ++c) {
        // ---- compute chunk c ----
        const char* sb = s_raw + (c & 1) * BUFB;
        const int cbase = (c % CPS) * CHUNK;
        #pragma unroll
        for (int tt = 0; tt < 2; ++tt) {
            const int p0 = (wave * 2 + tt) * 16;
            f32x4 acc[6] = {};
            #pragma unroll
            for (int t = 0; t < KT; ++t) {
                const int row = p0 + r16 + t;
                const int swz = ((row >> 2) & 3) << 4;
                const char* ap = sb + row * RSB;
                #pragma unroll
                for (int ks = 0; ks < KS; ++ks) {
                    f16x8 af = *(const f16x8*)(ap + ((ks * 64 + g * 16) ^ swz));
                    #pragma unroll
                    for (int c6 = 0; c6 < 6; ++c6)
                        acc[c6] = __builtin_amdgcn_mfma_f32_16x16x32_f16(af, bf[t][ks][c6], acc[c6], 0, 0, 0);
                }
            }
            const int prow = cbase + p0 + g * 4;   // C/D: col=lane&15, row=g*4+i
            if (prow + 3 < LOUT) {
                #pragma unroll
                for (int c6 = 0; c6 < 6; ++c6)
                    #pragma unroll
                    for (int i = 0; i < 4; ++i) runmax[c6] = fmaxf(runmax[c6], acc[c6][i]);
            } else {
                #pragma unroll
                for (int c6 = 0; c6 < 6; ++c6)
                    #pragma unroll
                    for (int i = 0; i < 4; ++i)
                        if (prow + i < LOUT) runmax[c6] = fmaxf(runmax[c6], acc[c6][i]);
            }
        }

        // ---- sample boundary: reduce + write feat ----
        if ((c % CPS) == CPS - 1) {
            #pragma unroll
            for (int c6 = 0; c6 < 6; ++c6) {
                runmax[c6] = fmaxf(runmax[c6], __shfl_xor(runmax[c6], 16, 64));
                runmax[c6] = fmaxf(runmax[c6], __shfl_xor(runmax[c6], 32, 64));
            }
            if (lane < 16) {
                #pragma unroll
                for (int c6 = 0; c6 < 6; ++c6)
                    s_red[wave * 96 + c6 * 16 + lane] = runmax[c6];
            }
            __syncthreads();
            if (tid < 96) {
                float m = fmaxf(fmaxf(s_red[tid], s_red[96 + tid]),
                                fmaxf(s_red[192 + tid], s_red[288 + tid]));
                feat[((size_t)blockIdx.x * NS + c / CPS) * 192 + feat_off + tid] =
                    fmaxf(m + bias[tid], 0.f);
            }
            #pragma unroll
            for (int c6 = 0; c6 < 6; ++c6) runmax[c6] = -3.0e38f;
        }

        // ---- stage chunk c+1 into LDS, issue loads for c+2 ----
        if (c + 1 < NC) {
            __syncthreads();                 // all waves done reading buf[(c+1)&1]
            do_write((c + 1) & 1);
            if (c + 2 < NC) do_loads(c + 2);
            __syncthreads();                 // writes visible for compute(c+1)
        }
    }
}

// ---------------------------------------------------------------------------
// Gram + L2 normalize + readout (4 samples/block, one wave each).
// ---------------------------------------------------------------------------
__global__ __launch_bounds__(256) void gram_affinity_kernel(
    const float* __restrict__ feat, const float* __restrict__ w_aff,
    const float* __restrict__ b_aff, float* __restrict__ out, int B)
{
    const int lane = threadIdx.x & 63;
    const int wid  = threadIdx.x >> 6;
    const int b    = blockIdx.x * 4 + wid;

    __shared__ float s_x[4][192];

    if (b < B) {
        const float* fp = feat + (size_t)b * 192;
        for (int i = lane; i < 192; i += 64) s_x[wid][i] = fp[i];
    }
    __syncthreads();

    if (b < B) {
        float ssum = 0.f, sdot = 0.f;
        #pragma unroll
        for (int t = 0; t < 16; ++t) {
            const int jk = t * 64 + lane;
            const int j = jk >> 5, k = jk & 31;
            float gg = 0.f;
            #pragma unroll
            for (int i = 0; i < 6; ++i)
                gg = fmaf(s_x[wid][i * 32 + j], s_x[wid][i * 32 + k], gg);
            ssum = fmaf(gg, gg, ssum);
            sdot = fmaf(gg, w_aff[jk], sdot);
        }
        #pragma unroll
        for (int off = 32; off >= 1; off >>= 1) {
            ssum += __shfl_xor(ssum, off, 64);
            sdot += __shfl_xor(sdot, off, 64);
        }
        if (lane == 0) out[b] = sdot / (sqrtf(ssum) + 1e-12f) + b_aff[0];
    }
}

extern "C" void kernel_launch(void* const* d_in, const int* in_sizes, int n_in,
                              void* d_out, int out_size, void* d_ws, size_t ws_size,
                              hipStream_t stream)
{
    const float* protein = (const float*)d_in[0];  // (B, 25, 1000)
    const float* ligand  = (const float*)d_in[1];  // (B, 64, 100)
    const float* w_pro   = (const float*)d_in[2];  // (96, 25, 8)
    const float* b_pro   = (const float*)d_in[3];  // (96,)
    const float* w_lig   = (const float*)d_in[4];  // (96, 64, 4)
    const float* b_lig   = (const float*)d_in[5];  // (96,)
    const float* w_aff   = (const float*)d_in[6];  // (1024,)
    const float* b_aff   = (const float*)d_in[7];  // (1,)
    float* out = (float*)d_out;
    const int B = out_size;                        // 4096

    float* feat   = (float*)d_ws;                              // (B,192) f32
    f16*   wpackP = (f16*)((char*)d_ws + (size_t)B * 192 * 4); // 8*96*32 f16
    f16*   wpackL = wpackP + 8 * 96 * 32;                      // 4*96*64 f16

    repack_kernel<25, 8, 32><<<96, 256, 0, stream>>>(w_pro, wpackP);
    repack_kernel<64, 4, 64><<<96, 256, 0, stream>>>(w_lig, wpackL);

    // ligand branch -> feat[:, 0:96]; 4 samples/block
    // V,L,KT,VP,KS,LOUT, NS,CPS,CHUNK,LPB,LPW,RSB
    conv_mfma_kernel<64, 100, 4, 64, 2, 97, 4, 1, 128, 136, 100, 144>
        <<<B / 4, 256, 0, stream>>>(ligand, wpackL, b_lig, feat, 0);
    // protein branch -> feat[:, 96:192]; 8 chunks of 128 positions
    conv_mfma_kernel<25, 1000, 8, 32, 1, 993, 1, 8, 128, 136, 136, 80>
        <<<B, 256, 0, stream>>>(protein, wpackP, b_pro, feat, 96);

    gram_affinity_kernel<<<(B + 3) / 4, 256, 0, stream>>>(feat, w_aff, b_aff, out, B);
}

// Round 5
// 687.015 us; speedup vs baseline: 2.0921x; 2.0921x over previous
//
#include <hip/hip_runtime.h>
#include <math.h>

typedef _Float16 f16;
typedef _Float16 f16x4 __attribute__((ext_vector_type(4)));
typedef _Float16 f16x8 __attribute__((ext_vector_type(8)));
typedef float f32x16 __attribute__((ext_vector_type(16)));

// ---------------------------------------------------------------------------
// Repack weights (96, V, K) fp32 -> wpack[t][ch][VP] f16, zero-padded v >= V.
// ---------------------------------------------------------------------------
template<int V, int K, int VP>
__global__ void repack_kernel(const float* __restrict__ w, f16* __restrict__ wp) {
    int i = blockIdx.x * 256 + threadIdx.x;
    if (i >= K * 96 * VP) return;
    int v = i % VP, ch = (i / VP) % 96, t = i / (VP * 96);
    float val = (v < V) ? w[(ch * V + v) * K + t] : 0.f;
    wp[i] = (f16)val;
}

// ---------------------------------------------------------------------------
// PROTEIN branch. 32x32x16 f16 MFMA implicit GEMM.
// Key fix vs r3/r4: full-N weight residency (bf = 192 VGPR) in the 512-reg
// tier: __launch_bounds__(256,1) -> 1 wave/SIMD, no spill below ~450 regs.
// Each A-fragment LDS read feeds 3 MFMAs (all 96 channels) -> LDS off the
// critical path (A-reads 8*12cyc < MFMA 48*8cyc per row-tile... per CU).
// Staging hidden by 2-half double-buffer: rs-loads for half h+2 issued
// before compute(h); LDS write after barrier (T14). 4 samples/block.
// ---------------------------------------------------------------------------
__global__ __launch_bounds__(256, 1) void conv_pro_kernel(
    const float* __restrict__ in,    // (B, 25, 1000) f32
    const f16*   __restrict__ wp,    // (8, 96, 32) f16
    const float* __restrict__ bias,  // (96)
    float* __restrict__ feat,        // (B, 192)
    int feat_off)
{
    constexpr int V = 25, L = 1000, KT = 8, VP = 32, LOUT = 993;
    constexpr int SPB = 4;            // samples per block
    constexpr int NH  = SPB * 2;      // halves (pipeline steps)
    constexpr int HR  = 520;          // rows per half-buffer (512 + 8 halo)
    constexpr int RSB = 80;           // row stride bytes (32 f16 payload + pad)
    constexpr int BUFB = HR * RSB;    // 41600 B per buffer
    constexpr int NIT  = 7 * HR;      // staging iterations (7 vocab-quads)
    constexpr int MAXU = (NIT + 255) / 256;   // 15

    __shared__ __align__(16) char s_raw[2 * BUFB];   // 83.2 KB
    __shared__ float s_red[4 * 96];

    const int tid  = threadIdx.x;
    const int wave = tid >> 6;
    const int lane = tid & 63;
    const int q    = lane >> 5;       // k-half
    const int r    = lane & 31;       // row/col in 32-tile
    const size_t b0 = (size_t)blockIdx.x * SPB;

    // ---- weights: all 8 taps x 2 ksteps x 3 col-tiles resident (192 VGPR) ----
    f16x8 bf[KT][2][3];
    #pragma unroll
    for (int t = 0; t < KT; ++t)
        #pragma unroll
        for (int ks = 0; ks < 2; ++ks)
            #pragma unroll
            for (int c = 0; c < 3; ++c)
                bf[t][ks][c] = *(const f16x8*)(wp + (t * 96 + c * 32 + r) * VP + ks * 16 + q * 8);

    // ---- register staging (60 VGPR) ----
    float rs[MAXU][4];
    auto do_loads = [&](int c) {
        const float* gs = in + (b0 + (c >> 1)) * (size_t)(V * L);
        const int g0 = (c & 1) * 512;
        #pragma unroll
        for (int u = 0; u < MAXU; ++u) {
            int uu = u * 256 + tid;
            int q4 = uu / HR, p = uu - q4 * HR;
            int g = g0 + p;
            bool ok = (uu < NIT) && (g < L);
            #pragma unroll
            for (int j = 0; j < 4; ++j) {
                int v = q4 * 4 + j;
                rs[u][j] = (ok && v < V) ? gs[(size_t)v * L + g] : 0.f;
            }
        }
    };
    auto do_write = [&](int bsel) {
        char* sb = s_raw + bsel * BUFB;
        #pragma unroll
        for (int u = 0; u < MAXU; ++u) {
            int uu = u * 256 + tid;
            if (uu < NIT) {
                int q4 = uu / HR, p = uu - q4 * HR;
                int swz = ((p >> 3) & 3) << 4;
                char* dst = sb + p * RSB;
                if (q4 < 6) {         // full quads: v = 4q4..4q4+3
                    f16x4 hv = { (f16)rs[u][0], (f16)rs[u][1], (f16)rs[u][2], (f16)rs[u][3] };
                    *(f16x4*)(dst + ((8 * q4) ^ swz)) = hv;
                } else {              // tail: v=24 + zero pad v25..31
                    f16x8 hv = {};
                    hv[0] = (f16)rs[u][0];
                    *(f16x8*)(dst + (48 ^ swz)) = hv;
                }
            }
        }
    };

    // ---- pipeline prologue ----
    do_loads(0);
    do_write(0);
    do_loads(1);
    __syncthreads();

    float runmax[3] = { -3.0e38f, -3.0e38f, -3.0e38f };

    for (int h = 0; h < NH; ++h) {
        const char* sb = s_raw + (h & 1) * BUFB;
        // 16 row-tiles per half, 4 per wave; each wave all 96 channels
        #pragma unroll
        for (int tt = 0; tt < 4; ++tt) {
            const int Tl = wave * 4 + tt;
            f32x16 acc[3] = {};
            #pragma unroll
            for (int t = 0; t < KT; ++t) {
                const int row = Tl * 32 + r + t;          // <= 518 < HR
                const int swz = ((row >> 3) & 3) << 4;
                const char* ap = sb + row * RSB;
                #pragma unroll
                for (int ks = 0; ks < 2; ++ks) {
                    f16x8 af = *(const f16x8*)(ap + ((ks * 32 + q * 16) ^ swz));
                    #pragma unroll
                    for (int c = 0; c < 3; ++c)
                        acc[c] = __builtin_amdgcn_mfma_f32_32x32x16_f16(af, bf[t][ks][c], acc[c], 0, 0, 0);
                }
            }
            const int p0g = (h & 1) * 512 + Tl * 32;
            if (p0g + 32 <= LOUT) {
                #pragma unroll
                for (int c = 0; c < 3; ++c)
                    #pragma unroll
                    for (int i = 0; i < 16; ++i) runmax[c] = fmaxf(runmax[c], acc[c][i]);
            } else {
                #pragma unroll
                for (int c = 0; c < 3; ++c)
                    #pragma unroll
                    for (int i = 0; i < 16; ++i) {
                        const int rr = (i & 3) + 8 * (i >> 2) + 4 * q;  // C/D row
                        if (p0g + rr < LOUT) runmax[c] = fmaxf(runmax[c], acc[c][i]);
                    }
            }
        }

        const bool send = (h & 1);
        if (send) {       // sample boundary: cross-lane + cross-wave max
            #pragma unroll
            for (int c = 0; c < 3; ++c)
                runmax[c] = fmaxf(runmax[c], __shfl_xor(runmax[c], 32, 64));
            if (lane < 32) {
                #pragma unroll
                for (int c = 0; c < 3; ++c) s_red[wave * 96 + c * 32 + r] = runmax[c];
            }
        }
        __syncthreads();   // (A) compute done + s_red visible
        if (send) {
            if (tid < 96) {
                float m = fmaxf(fmaxf(s_red[tid], s_red[96 + tid]),
                                fmaxf(s_red[192 + tid], s_red[288 + tid]));
                feat[(b0 + (h >> 1)) * 192 + feat_off + tid] = fmaxf(m + bias[tid], 0.f);
            }
            #pragma unroll
            for (int c = 0; c < 3; ++c) runmax[c] = -3.0e38f;
        }
        if (h + 1 < NH) {
            do_write((h + 1) & 1);     // stage next half from rs
            if (h + 2 < NH) do_loads(h + 2);   // issue loads 2 ahead
            __syncthreads();           // (B) staging visible
        }
    }
}

// ---------------------------------------------------------------------------
// LIGAND branch: round-2 kernel (proven; small share of runtime).
// 6 waves: colw = wave%3 (32 ch), roww = wave/3 (2 row-tiles each).
// ---------------------------------------------------------------------------
__global__ __launch_bounds__(384) void conv_lig_kernel(
    const float* __restrict__ in,    // (B, 64, 100) f32
    const f16*   __restrict__ wp,    // (4, 96, 64) f16
    const float* __restrict__ bias,  // (96)
    float* __restrict__ feat,        // (B, 192)
    int feat_off)
{
    constexpr int V = 64, L = 100, KT = 4, VP = 64, KSTEPS = 4;
    constexpr int LP = 132, RS = 72, NTILES = 4, LOUT = 97;
    constexpr int RSB = RS * 2, NQ = V / 4;
    __shared__ __align__(16) char s_raw[LP * RSB];

    const int tid  = threadIdx.x;
    const int b    = blockIdx.x;
    const int wave = tid >> 6;
    const int lane = tid & 63;
    const int colw = wave % 3;
    const int roww = wave / 3;
    const int q    = lane >> 5;
    const int r    = lane & 31;

    {   // zero LDS (covers row pad)
        float4 z = {0.f, 0.f, 0.f, 0.f};
        float4* sz = (float4*)s_raw;
        for (int i = tid; i < LP * RSB / 16; i += 384) sz[i] = z;
    }
    __syncthreads();

    const float* gin = in + (size_t)b * (V * L);
    for (int i = tid; i < NQ * L; i += 384) {
        int q4 = i / L, p = i - q4 * L;
        const float* gp = gin + q4 * 4 * L + p;
        f16x4 hv = { (f16)gp[0], (f16)gp[L], (f16)gp[2 * L], (f16)gp[3 * L] };
        int off = (8 * q4) ^ (((p >> 3) & 3) << 4);
        *(f16x4*)(s_raw + p * RSB + off) = hv;
    }

    f16x8 bfr[KT][KSTEPS];
    #pragma unroll
    for (int t = 0; t < KT; ++t)
        #pragma unroll
        for (int ks = 0; ks < KSTEPS; ++ks)
            bfr[t][ks] = *(const f16x8*)(wp + (t * 96 + colw * 32 + r) * VP + ks * 16 + q * 8);

    __syncthreads();

    float runmax = -3.0e38f;
    for (int it = 0; it < NTILES / 2; ++it) {
        const int p0 = (roww * (NTILES / 2) + it) * 32;
        f32x16 acc = {};
        #pragma unroll
        for (int t = 0; t < KT; ++t) {
            int row = p0 + r + t;
            if (row > LP - 1) row = LP - 1;          // clamped row is zero
            const char* ap = s_raw + row * RSB;
            const int swz = ((row >> 3) & 3) << 4;
            #pragma unroll
            for (int ks = 0; ks < KSTEPS; ++ks) {
                f16x8 af = *(const f16x8*)(ap + ((ks * 32 + q * 16) ^ swz));
                acc = __builtin_amdgcn_mfma_f32_32x32x16_f16(af, bfr[t][ks], acc, 0, 0, 0);
            }
        }
        #pragma unroll
        for (int i = 0; i < 16; ++i) {
            int rr = (i & 3) + 8 * (i >> 2) + 4 * q;
            if (p0 + rr < LOUT) runmax = fmaxf(runmax, acc[i]);
        }
    }
    runmax = fmaxf(runmax, __shfl_xor(runmax, 32, 64));

    __syncthreads();
    float* s_red = (float*)s_raw;     // [2][96]
    if (lane < 32) s_red[roww * 96 + colw * 32 + r] = runmax;
    __syncthreads();
    if (tid < 96) {
        float m = fmaxf(s_red[tid], s_red[96 + tid]);
        feat[(size_t)b * 192 + feat_off + tid] = fmaxf(m + bias[tid], 0.f);
    }
}

// ---------------------------------------------------------------------------
// Gram + L2 normalize + readout (4 samples/block, one wave each).
// ---------------------------------------------------------------------------
__global__ __launch_bounds__(256) void gram_affinity_kernel(
    const float* __restrict__ feat, const float* __restrict__ w_aff,
    const float* __restrict__ b_aff, float* __restrict__ out, int B)
{
    const int lane = threadIdx.x & 63;
    const int wid  = threadIdx.x >> 6;
    const int b    = blockIdx.x * 4 + wid;

    __shared__ float s_x[4][192];

    if (b < B) {
        const float* fp = feat + (size_t)b * 192;
        for (int i = lane; i < 192; i += 64) s_x[wid][i] = fp[i];
    }
    __syncthreads();

    if (b < B) {
        float ssum = 0.f, sdot = 0.f;
        #pragma unroll
        for (int t = 0; t < 16; ++t) {
            const int jk = t * 64 + lane;
            const int j = jk >> 5, k = jk & 31;
            float gg = 0.f;
            #pragma unroll
            for (int i = 0; i < 6; ++i)
                gg = fmaf(s_x[wid][i * 32 + j], s_x[wid][i * 32 + k], gg);
            ssum = fmaf(gg, gg, ssum);
            sdot = fmaf(gg, w_aff[jk], sdot);
        }
        #pragma unroll
        for (int off = 32; off >= 1; off >>= 1) {
            ssum += __shfl_xor(ssum, off, 64);
            sdot += __shfl_xor(sdot, off, 64);
        }
        if (lane == 0) out[b] = sdot / (sqrtf(ssum) + 1e-12f) + b_aff[0];
    }
}

extern "C" void kernel_launch(void* const* d_in, const int* in_sizes, int n_in,
                              void* d_out, int out_size, void* d_ws, size_t ws_size,
                              hipStream_t stream)
{
    const float* protein = (const float*)d_in[0];  // (B, 25, 1000)
    const float* ligand  = (const float*)d_in[1];  // (B, 64, 100)
    const float* w_pro   = (const float*)d_in[2];  // (96, 25, 8)
    const float* b_pro   = (const float*)d_in[3];  // (96,)
    const float* w_lig   = (const float*)d_in[4];  // (96, 64, 4)
    const float* b_lig   = (const float*)d_in[5];  // (96,)
    const float* w_aff   = (const float*)d_in[6];  // (1024,)
    const float* b_aff   = (const float*)d_in[7];  // (1,)
    float* out = (float*)d_out;
    const int B = out_size;                        // 4096

    float* feat   = (float*)d_ws;                              // (B,192) f32
    f16*   wpackP = (f16*)((char*)d_ws + (size_t)B * 192 * 4); // 8*96*32 f16
    f16*   wpackL = wpackP + 8 * 96 * 32;                      // 4*96*64 f16

    repack_kernel<25, 8, 32><<<96, 256, 0, stream>>>(w_pro, wpackP);
    repack_kernel<64, 4, 64><<<96, 256, 0, stream>>>(w_lig, wpackL);

    // ligand branch -> feat[:, 0:96]
    conv_lig_kernel<<<B, 384, 0, stream>>>(ligand, wpackL, b_lig, feat, 0);
    // protein branch -> feat[:, 96:192]; 4 samples/block, 512-reg waves
    conv_pro_kernel<<<B / 4, 256, 0, stream>>>(protein, wpackP, b_pro, feat, 96);

    gram_affinity_kernel<<<(B + 3) / 4, 256, 0, stream>>>(feat, w_aff, b_aff, out, B);
}